// Round 12
// baseline (108.232 us; speedup 1.0000x reference)
//
#include <hip/hip_runtime.h>

#define NJ 15
#define FOCALC 575.0f
#define PXC 320.0f
#define PYC 240.0f

constexpr int THREADS = 64;    // ONE wave per block: no barriers, private pipeline
constexpr int BLOCKS  = 1792;  // 7 blocks/CU * 256 CUs
constexpr int TILE    = 64;    // frames per tile

// Tile region layout (floats): [0,1920) bone | [1920,2496) R | [2496,2688) C
constexpr int OFF_R = TILE * 30;                  // 1920
constexpr int OFF_C = TILE * 30 + TILE * 9;       // 2496
constexpr int TILE_FLOATS = TILE * 42;            // 2688 floats = 10752 B
constexpr int B_BYTES  = TILE * 30 * 4;           // 7680  (16B-aligned)
constexpr int BR_BYTES = B_BYTES + TILE * 9 * 4;  // 9984  (16B-aligned)

// Direct global->LDS async copy. LDS dest = wave-uniform base + lane*size;
// global src is per-lane. size must be a literal.
__device__ __forceinline__ void load_lds16(const void* g, float* lds) {
    __builtin_amdgcn_global_load_lds(
        (const __attribute__((address_space(1))) void*)g,
        (__attribute__((address_space(3))) void*)lds,
        16, 0, 0);
}
__device__ __forceinline__ void load_lds4(const void* g, float* lds) {
    __builtin_amdgcn_global_load_lds(
        (const __attribute__((address_space(1))) void*)g,
        (__attribute__((address_space(3))) void*)lds,
        4, 0, 0);
}

__global__ __launch_bounds__(THREADS) void proj_fused_kernel(
        const float* __restrict__ pose3d,   // [3][15]
        const float* __restrict__ bone2d,   // [N][30]
        const float* __restrict__ R,        // [N][9]
        const float* __restrict__ C,        // [N][3]
        float* __restrict__ partial,        // [BLOCKS]
        unsigned int* __restrict__ counter, // [1], memset to 0 each call
        float* __restrict__ out,
        int N) {
    __shared__ float sA[TILE_FLOATS];   // 10752 B
    __shared__ float sB[TILE_FLOATS];   // 10752 B -> ~21.7 KB: 7 blocks/CU
    __shared__ float p3d[3 * NJ];

    const int lane = threadIdx.x;       // 0..63
    if (lane < 3 * NJ) p3d[lane] = pose3d[lane];
    __syncthreads();                    // once; single-wave barrier is cheap

    const int nFull = N / TILE;         // full tiles only (remainder in epilogue)
    int myT = 0;
    if ((int)blockIdx.x < nFull)
        myT = (nFull - blockIdx.x + BLOCKS - 1) / BLOCKS;

    // stage one full tile -> buf. EXACTLY 12 VMEM instructions (vmcnt math).
    auto stage = [&](float* buf, int tile) {
        const long base = (long)tile * TILE;
        const char* gb = (const char*)(bone2d + base * 30);
        const char* gr = (const char*)(R      + base * 9);
        const char* gc = (const char*)(C      + base * 3);
        #pragma unroll
        for (int k = 0; k < 10; ++k) {              // 10 x 1KB, size-16
            int o = k * 1024 + lane * 16;           // per-lane byte offset
            const void* g = (o < B_BYTES)  ? (const void*)(gb + o)
                          : (o < BR_BYTES) ? (const void*)(gr + (o - B_BYTES))
                                           : (const void*)(gc + (o - BR_BYTES));
            load_lds16(g, buf + k * 256);
        }
        #pragma unroll
        for (int k = 0; k < 2; ++k) {               // 2 x 256B tail, size-4 (C region)
            int o = 10240 + k * 256 + lane * 4;     // o >= 10240 > BR_BYTES
            load_lds4((const void*)(gc + (o - BR_BYTES)), buf + 2560 + k * 64);
        }
    };

    if (myT > 0) stage(sA, blockIdx.x);
    if (myT > 1) stage(sB, blockIdx.x + BLOCKS);

    float acc = 0.0f;
    for (int k = 0; k < myT; ++k) {
        float* buf = (k & 1) ? sB : sA;
        // wait for tile k's 12 loads; keep tile k+1's 12 in flight
        if (k < myT - 1) asm volatile("s_waitcnt vmcnt(12)" ::: "memory");
        else             asm volatile("s_waitcnt vmcnt(0)"  ::: "memory");
        __builtin_amdgcn_sched_barrier(0);

        const int f = lane;   // one whole frame per lane
        const float* Rl = buf + OFF_R + f * 9;   // stride 9: conflict-free
        float r0 = Rl[0], r1 = Rl[1], r2 = Rl[2];
        float r3 = Rl[3], r4 = Rl[4], r5 = Rl[5];
        float r6 = Rl[6], r7 = Rl[7], r8 = Rl[8];
        const float* Cl = buf + OFF_C + f * 3;   // stride 3: conflict-free
        float c0 = Cl[0], c1 = Cl[1], c2 = Cl[2];

        float bf[30];                            // bone as 15 x float2 (8B-aligned)
        const float2* bl2 = (const float2*)(buf + f * 30);
        #pragma unroll
        for (int t = 0; t < 15; ++t) {
            float2 w = bl2[t];
            bf[2 * t]     = w.x;
            bf[2 * t + 1] = w.y;
        }

        float fs = 0.0f;
        #pragma unroll
        for (int j = 0; j < NJ; ++j) {
            float x0 = p3d[j] - c0;
            float x1 = p3d[NJ + j] - c1;
            float x2 = p3d[2 * NJ + j] - c2;
            // P_cam[c] = sum_k R[k][c] * X[k]   (einsum 'nkc,nkj->ncj')
            float pc0 = r0 * x0 + r3 * x1 + r6 * x2;
            float pc1 = r1 * x0 + r4 * x1 + r7 * x2;
            float pc2 = r2 * x0 + r5 * x1 + r8 * x2;
            float w = FOCALC / pc2;
            float u = pc0 * w + PXC;
            float v = pc1 * w + PYC;
            float du = u - bf[j];
            float dv = v - bf[NJ + j];
            fs += du * du + dv * dv;
        }
        acc += fs / 30.0f;

        __builtin_amdgcn_sched_barrier(0);       // keep stage AFTER compute's ds_reads
        if (k + 2 < myT) stage(buf, blockIdx.x + (k + 2) * BLOCKS);
    }

    // wave-level reduction (single wave per block)
    #pragma unroll
    for (int off = 32; off > 0; off >>= 1)
        acc += __shfl_down(acc, off, 64);
    if (lane == 0) partial[blockIdx.x] = acc;

    // ---- last-block-done epilogue (deterministic fixed-order reduction) ----
    __threadfence();                       // release partial write (device scope)
    unsigned int ticket = 0;
    if (lane == 0) ticket = atomicAdd(counter, 1u);
    ticket = __shfl(ticket, 0, 64);
    if (ticket == (unsigned int)(gridDim.x - 1)) {
        __threadfence();                   // acquire: see all partials

        // fixed-order sum: lane i sums partial[i], [i+64], ... then tree-reduce
        float a = 0.0f;
        for (int i = lane; i < BLOCKS; i += 64)
            a += partial[i];

        // remainder frames (N % TILE; empty for N=1e6)
        const int rem0 = nFull * TILE;
        for (int n = rem0 + lane; n < N; n += 64) {
            const float* Rp = R + 9 * (long)n;
            float r0 = Rp[0], r1 = Rp[1], r2 = Rp[2];
            float r3 = Rp[3], r4 = Rp[4], r5 = Rp[5];
            float r6 = Rp[6], r7 = Rp[7], r8 = Rp[8];
            const float* Cp = C + 3 * (long)n;
            float c0 = Cp[0], c1 = Cp[1], c2 = Cp[2];
            const float* b = bone2d + 30 * (long)n;
            float fs = 0.0f;
            #pragma unroll
            for (int j = 0; j < NJ; ++j) {
                float x0 = p3d[j] - c0;
                float x1 = p3d[NJ + j] - c1;
                float x2 = p3d[2 * NJ + j] - c2;
                float pc0 = r0 * x0 + r3 * x1 + r6 * x2;
                float pc1 = r1 * x0 + r4 * x1 + r7 * x2;
                float pc2 = r2 * x0 + r5 * x1 + r8 * x2;
                float w = FOCALC / pc2;
                float u = pc0 * w + PXC;
                float v = pc1 * w + PYC;
                float du = u - b[j];
                float dv = v - b[NJ + j];
                fs += du * du + dv * dv;
            }
            a += fs / 30.0f;
        }

        #pragma unroll
        for (int off = 32; off > 0; off >>= 1)
            a += __shfl_down(a, off, 64);

        if (lane == 0) {
            const int lb[6][2] = {{0,1},{1,2},{2,3},{8,9},{9,10},{10,11}};
            const int rb[6][2] = {{0,4},{4,5},{5,6},{8,12},{12,13},{13,14}};
            float sym = 0.0f;
            #pragma unroll
            for (int bb = 0; bb < 6; ++bb) {
                float ll = 0.0f, lr = 0.0f;
                #pragma unroll
                for (int k = 0; k < 3; ++k) {
                    float dl = p3d[k * NJ + lb[bb][0]] - p3d[k * NJ + lb[bb][1]];
                    float dr = p3d[k * NJ + rb[bb][0]] - p3d[k * NJ + rb[bb][1]];
                    ll += dl * dl;
                    lr += dr * dr;
                }
                float d = ll - lr;
                sym += d * d;
            }
            sym /= 6.0f;
            out[0] = 1.0f * sym + 1.0f * a;
        }
    }
}

extern "C" void kernel_launch(void* const* d_in, const int* in_sizes, int n_in,
                              void* d_out, int out_size, void* d_ws, size_t ws_size,
                              hipStream_t stream) {
    const float* pose3d = (const float*)d_in[0];
    const float* bone2d = (const float*)d_in[1];
    const float* R      = (const float*)d_in[2];
    const float* C      = (const float*)d_in[3];
    float* out = (float*)d_out;
    float* partial = (float*)d_ws;                           // BLOCKS floats
    unsigned int* counter = (unsigned int*)((char*)d_ws + BLOCKS * sizeof(float));

    int N = in_sizes[3] / 3;  // C_drone has N*3 elements

    hipMemsetAsync(counter, 0, sizeof(unsigned int), stream);  // capturable node
    proj_fused_kernel<<<BLOCKS, THREADS, 0, stream>>>(
        pose3d, bone2d, R, C, partial, counter, out, N);
}

// Round 14
// 52.161 us; speedup vs baseline: 2.0750x; 2.0750x over previous
//
#include <hip/hip_runtime.h>

#define NJ 15
#define FOCALC 575.0f
#define PXC 320.0f
#define PYC 240.0f

constexpr int THREADS = 64;    // ONE wave per block: private pipeline, no barriers
constexpr int BLOCKS  = 1280;  // 5 blocks/CU * 256 CUs (LDS-limited, all resident)
constexpr int TILE    = 64;    // frames per tile

// Tile region layout (floats): [0,1920) bone | [1920,2496) R | [2496,2688) C
constexpr int OFF_R = TILE * 30;                  // 1920
constexpr int OFF_C = TILE * 30 + TILE * 9;       // 2496
constexpr int TILE_FLOATS = TILE * 42;            // 2688 floats = 10752 B
constexpr int B_BYTES  = TILE * 30 * 4;           // 7680  (16B-aligned)
constexpr int BR_BYTES = B_BYTES + TILE * 9 * 4;  // 9984  (16B-aligned)

// Direct global->LDS async copy. LDS dest = wave-uniform base + lane*size;
// global src is per-lane. size must be a literal.
__device__ __forceinline__ void load_lds16(const void* g, float* lds) {
    __builtin_amdgcn_global_load_lds(
        (const __attribute__((address_space(1))) void*)g,
        (__attribute__((address_space(3))) void*)lds,
        16, 0, 0);
}
__device__ __forceinline__ void load_lds4(const void* g, float* lds) {
    __builtin_amdgcn_global_load_lds(
        (const __attribute__((address_space(1))) void*)g,
        (__attribute__((address_space(3))) void*)lds,
        4, 0, 0);
}

__global__ __launch_bounds__(THREADS) void proj_partial_kernel(
        const float* __restrict__ pose3d,   // [3][15]
        const float* __restrict__ bone2d,   // [N][30]
        const float* __restrict__ R,        // [N][9]
        const float* __restrict__ C,        // [N][3]
        float* __restrict__ partial,        // [BLOCKS]
        int N) {
    __shared__ float sA[TILE_FLOATS];   // 3 x 10752 B = 32.25 KB -> 5 blocks/CU
    __shared__ float sB[TILE_FLOATS];
    __shared__ float sC[TILE_FLOATS];
    __shared__ float p3d[3 * NJ];

    const int lane = threadIdx.x;       // 0..63
    if (lane < 3 * NJ) p3d[lane] = pose3d[lane];
    __syncthreads();                    // once; single-wave barrier is cheap

    const int nFull = N / TILE;         // full tiles only (remainder -> finalize)
    int myT = 0;
    if ((int)blockIdx.x < nFull)
        myT = (nFull - blockIdx.x + BLOCKS - 1) / BLOCKS;

    // stage one full tile -> buf. EXACTLY 12 VMEM instructions (vmcnt math).
    auto stage = [&](float* buf, int tile) {
        const long base = (long)tile * TILE;
        const char* gb = (const char*)(bone2d + base * 30);
        const char* gr = (const char*)(R      + base * 9);
        const char* gc = (const char*)(C      + base * 3);
        #pragma unroll
        for (int k = 0; k < 10; ++k) {              // 10 x 1KB, size-16
            int o = k * 1024 + lane * 16;           // per-lane byte offset
            const void* g = (o < B_BYTES)  ? (const void*)(gb + o)
                          : (o < BR_BYTES) ? (const void*)(gr + (o - B_BYTES))
                                           : (const void*)(gc + (o - BR_BYTES));
            load_lds16(g, buf + k * 256);
        }
        #pragma unroll
        for (int k = 0; k < 2; ++k) {               // 2 x 256B tail, size-4 (C region)
            int o = 10240 + k * 256 + lane * 4;     // o >= 10240 > BR_BYTES
            load_lds4((const void*)(gc + (o - BR_BYTES)), buf + 2560 + k * 64);
        }
    };

    if (myT > 0) stage(sA, blockIdx.x);
    if (myT > 1) stage(sB, blockIdx.x + BLOCKS);
    if (myT > 2) stage(sC, blockIdx.x + 2 * BLOCKS);

    float acc = 0.0f;
    int sel = 0;                        // 0,1,2 round-robin; no pointer array
    for (int k = 0; k < myT; ++k) {
        // wait for tile k's 12 loads; keep up to 2 tiles (24 loads) in flight
        const int inflight = myT - 1 - k;
        if (inflight >= 2)      asm volatile("s_waitcnt vmcnt(24)" ::: "memory");
        else if (inflight == 1) asm volatile("s_waitcnt vmcnt(12)" ::: "memory");
        else                    asm volatile("s_waitcnt vmcnt(0)"  ::: "memory");
        __builtin_amdgcn_sched_barrier(0);

        float* buf = (sel == 0) ? sA : (sel == 1) ? sB : sC;

        const int f = lane;   // one whole frame per lane
        const float* Rl = buf + OFF_R + f * 9;   // stride 9: conflict-free
        float r0 = Rl[0], r1 = Rl[1], r2 = Rl[2];
        float r3 = Rl[3], r4 = Rl[4], r5 = Rl[5];
        float r6 = Rl[6], r7 = Rl[7], r8 = Rl[8];
        const float* Cl = buf + OFF_C + f * 3;   // stride 3: conflict-free
        float c0 = Cl[0], c1 = Cl[1], c2 = Cl[2];

        float bf[30];                            // bone as 15 x float2 (8B-aligned)
        const float2* bl2 = (const float2*)(buf + f * 30);
        #pragma unroll
        for (int t = 0; t < 15; ++t) {
            float2 w = bl2[t];
            bf[2 * t]     = w.x;
            bf[2 * t + 1] = w.y;
        }

        float fs = 0.0f;
        #pragma unroll
        for (int j = 0; j < NJ; ++j) {
            float x0 = p3d[j] - c0;
            float x1 = p3d[NJ + j] - c1;
            float x2 = p3d[2 * NJ + j] - c2;
            // P_cam[c] = sum_k R[k][c] * X[k]   (einsum 'nkc,nkj->ncj')
            float pc0 = r0 * x0 + r3 * x1 + r6 * x2;
            float pc1 = r1 * x0 + r4 * x1 + r7 * x2;
            float pc2 = r2 * x0 + r5 * x1 + r8 * x2;
            float w = FOCALC / pc2;
            float u = pc0 * w + PXC;
            float v = pc1 * w + PYC;
            float du = u - bf[j];
            float dv = v - bf[NJ + j];
            fs += du * du + dv * dv;
        }
        acc += fs / 30.0f;

        __builtin_amdgcn_sched_barrier(0);       // keep stage AFTER compute's ds_reads
        if (k + 3 < myT) stage(buf, blockIdx.x + (k + 3) * BLOCKS);
        sel = (sel == 2) ? 0 : sel + 1;
    }

    // wave-level reduction (single wave per block)
    #pragma unroll
    for (int off = 32; off > 0; off >>= 1)
        acc += __shfl_down(acc, off, 64);
    if (lane == 0) partial[blockIdx.x] = acc;
}

__global__ __launch_bounds__(256) void finalize_kernel(
        const float* __restrict__ partial,
        const float* __restrict__ pose3d,
        const float* __restrict__ bone2d,
        const float* __restrict__ R,
        const float* __restrict__ C,
        float* __restrict__ out,
        int nPartial, int N) {
    __shared__ float s[4];
    float acc = 0.0f;
    for (int i = threadIdx.x; i < nPartial; i += blockDim.x)
        acc += partial[i];

    // remainder frames (N % TILE) via direct global loads (empty for N=1e6)
    const int rem0 = (N / TILE) * TILE;
    for (int n = rem0 + threadIdx.x; n < N; n += blockDim.x) {
        const float* Rp = R + 9 * (long)n;
        float r0 = Rp[0], r1 = Rp[1], r2 = Rp[2];
        float r3 = Rp[3], r4 = Rp[4], r5 = Rp[5];
        float r6 = Rp[6], r7 = Rp[7], r8 = Rp[8];
        const float* Cp = C + 3 * (long)n;
        float c0 = Cp[0], c1 = Cp[1], c2 = Cp[2];
        const float* b = bone2d + 30 * (long)n;
        float fs = 0.0f;
        #pragma unroll
        for (int j = 0; j < NJ; ++j) {
            float x0 = pose3d[j] - c0;
            float x1 = pose3d[NJ + j] - c1;
            float x2 = pose3d[2 * NJ + j] - c2;
            float pc0 = r0 * x0 + r3 * x1 + r6 * x2;
            float pc1 = r1 * x0 + r4 * x1 + r7 * x2;
            float pc2 = r2 * x0 + r5 * x1 + r8 * x2;
            float w = FOCALC / pc2;
            float u = pc0 * w + PXC;
            float v = pc1 * w + PYC;
            float du = u - b[j];
            float dv = v - b[NJ + j];
            fs += du * du + dv * dv;
        }
        acc += fs / 30.0f;
    }

    // block reduce (256 threads)
    int lane = threadIdx.x & 63;
    int wid  = threadIdx.x >> 6;
    #pragma unroll
    for (int off = 32; off > 0; off >>= 1)
        acc += __shfl_down(acc, off, 64);
    if (lane == 0) s[wid] = acc;
    __syncthreads();
    if (threadIdx.x == 0) {
        acc = s[0] + s[1] + s[2] + s[3];
        const int lb[6][2] = {{0,1},{1,2},{2,3},{8,9},{9,10},{10,11}};
        const int rb[6][2] = {{0,4},{4,5},{5,6},{8,12},{12,13},{13,14}};
        float sym = 0.0f;
        #pragma unroll
        for (int bb = 0; bb < 6; ++bb) {
            float ll = 0.0f, lr = 0.0f;
            #pragma unroll
            for (int k = 0; k < 3; ++k) {
                float dl = pose3d[k * NJ + lb[bb][0]] - pose3d[k * NJ + lb[bb][1]];
                float dr = pose3d[k * NJ + rb[bb][0]] - pose3d[k * NJ + rb[bb][1]];
                ll += dl * dl;
                lr += dr * dr;
            }
            float d = ll - lr;
            sym += d * d;
        }
        sym /= 6.0f;
        out[0] = 1.0f * sym + 1.0f * acc;
    }
}

extern "C" void kernel_launch(void* const* d_in, const int* in_sizes, int n_in,
                              void* d_out, int out_size, void* d_ws, size_t ws_size,
                              hipStream_t stream) {
    const float* pose3d = (const float*)d_in[0];
    const float* bone2d = (const float*)d_in[1];
    const float* R      = (const float*)d_in[2];
    const float* C      = (const float*)d_in[3];
    float* out = (float*)d_out;
    float* partial = (float*)d_ws;

    int N = in_sizes[3] / 3;  // C_drone has N*3 elements

    proj_partial_kernel<<<BLOCKS, THREADS, 0, stream>>>(pose3d, bone2d, R, C, partial, N);
    finalize_kernel<<<1, 256, 0, stream>>>(partial, pose3d, bone2d, R, C, out, BLOCKS, N);
}

// Round 15
// 36.577 us; speedup vs baseline: 2.9590x; 1.4261x over previous
//
#include <hip/hip_runtime.h>

#define NJ 15
#define FOCALC 575.0f
#define PXC 320.0f
#define PYC 240.0f

constexpr int THREADS = 256;
constexpr int BLOCKS  = 2048;
constexpr int TILE    = 128;   // frames per tile (double-buffered)

// Tile region layout (floats): [0,3840) bone | [3840,4992) R | [4992,5376) C
constexpr int OFF_R = TILE * 30;            // 3840
constexpr int OFF_C = TILE * 30 + TILE * 9; // 4992
constexpr int TILE_FLOATS = TILE * 42;      // 5376 floats = 21504 B = 21 KB chunks
constexpr int B_BYTES  = TILE * 30 * 4;     // 15360
constexpr int BR_BYTES = B_BYTES + TILE * 9 * 4; // 19968
constexpr int CHUNKS   = 21;                // 21504 / 1024

// Direct global->LDS async copy, 16 B/lane (1 KB per wave-instruction).
// LDS dest = wave-uniform base + lane*16; global src is per-lane.
__device__ __forceinline__ void load_lds16(const void* g, float* lds) {
    __builtin_amdgcn_global_load_lds(
        (const __attribute__((address_space(1))) void*)g,
        (__attribute__((address_space(3))) void*)lds,
        16, 0, 0);
}

__device__ __forceinline__ float block_reduce_sum(float val) {
    __shared__ float s[THREADS / 64];
    int lane = threadIdx.x & 63;
    int wid  = threadIdx.x >> 6;
    #pragma unroll
    for (int off = 32; off > 0; off >>= 1)
        val += __shfl_down(val, off, 64);
    if (lane == 0) s[wid] = val;
    __syncthreads();
    if (wid == 0) {
        val = (lane < (THREADS / 64)) ? s[lane] : 0.0f;
        #pragma unroll
        for (int off = (THREADS / 128); off > 0; off >>= 1)
            val += __shfl_down(val, off, 64);
    }
    return val;  // valid in thread 0
}

__global__ __launch_bounds__(THREADS) void proj_partial_kernel(
        const float* __restrict__ pose3d,   // [3][15]
        const float* __restrict__ bone2d,   // [N][30]
        const float* __restrict__ R,        // [N][9]
        const float* __restrict__ C,        // [N][3]
        float* __restrict__ partial,        // [BLOCKS]
        int N) {
    __shared__ float sT0[TILE_FLOATS];
    __shared__ float sT1[TILE_FLOATS];
    __shared__ float p3d[3 * NJ];
    if (threadIdx.x < 3 * NJ) p3d[threadIdx.x] = pose3d[threadIdx.x];

    const int wid  = threadIdx.x >> 6;   // 4 waves
    const int lane = threadIdx.x & 63;
    const int nTiles = (N + TILE - 1) / TILE;

    // stage tile -> LDS buffer (async for full tiles; drained by __syncthreads)
    auto stage = [&](float* buf, int tile) {
        const int base = tile * TILE;
        const int cnt  = min(TILE, N - base);
        if (cnt == TILE) {
            const char* gb = (const char*)(bone2d + (long)base * 30);
            const char* gr = (const char*)(R      + (long)base * 9);
            const char* gc = (const char*)(C      + (long)base * 3);
            const int lo = lane * 16;
            #pragma unroll
            for (int k = 0; k < 6; ++k) {
                int c = wid + 4 * k;          // 0..23, wave-uniform guard
                if (c < CHUNKS) {
                    int o = c * 1024 + lo;    // byte offset in combined region
                    const void* g = (o < B_BYTES)  ? (const void*)(gb + o)
                                  : (o < BR_BYTES) ? (const void*)(gr + (o - B_BYTES))
                                                   : (const void*)(gc + (o - BR_BYTES));
                    load_lds16(g, buf + c * 256);
                }
            }
        } else {
            // remainder tile (one block, once): coalesced scalar staging
            for (int i = threadIdx.x; i < cnt * 30; i += THREADS)
                buf[i] = bone2d[(long)base * 30 + i];
            for (int i = threadIdx.x; i < cnt * 9; i += THREADS)
                buf[OFF_R + i] = R[(long)base * 9 + i];
            for (int i = threadIdx.x; i < cnt * 3; i += THREADS)
                buf[OFF_C + i] = C[(long)base * 3 + i];
        }
    };

    float acc = 0.0f;
    const int t0 = blockIdx.x;
    if (t0 < nTiles) stage(sT0, t0);
    __syncthreads();   // drains prologue loads (vmcnt(0)) + p3d writes

    const int f    = threadIdx.x & (TILE - 1);
    const int half = threadIdx.x >> 7;   // wave-uniform: waves 0,1 -> 0; 2,3 -> 1

    int cur = 0;
    for (int t = t0; t < nTiles; t += gridDim.x) {
        float* bufC = cur ? sT1 : sT0;   // compute buffer
        float* bufS = cur ? sT0 : sT1;   // stage buffer
        int nxt = t + gridDim.x;
        if (nxt < nTiles) stage(bufS, nxt);   // issue BEFORE compute: latency hidden

        const int cnt = min(TILE, N - t * TILE);
        if (f < cnt) {
            const float* Rl = bufC + OFF_R + f * 9;   // stride 9: conflict-free
            float r0 = Rl[0], r1 = Rl[1], r2 = Rl[2];
            float r3 = Rl[3], r4 = Rl[4], r5 = Rl[5];
            float r6 = Rl[6], r7 = Rl[7], r8 = Rl[8];
            const float* Cl = bufC + OFF_C + f * 3;   // stride 3: conflict-free
            float c0 = Cl[0], c1 = Cl[1], c2 = Cl[2];
            const float* bl = bufC + f * 30;          // stride 30

            float fs = 0.0f;
            auto term = [&](int j) {
                float x0 = p3d[j] - c0;
                float x1 = p3d[NJ + j] - c1;
                float x2 = p3d[2 * NJ + j] - c2;
                // P_cam[c] = sum_k R[k][c] * X[k]   (einsum 'nkc,nkj->ncj')
                float pc0 = r0 * x0 + r3 * x1 + r6 * x2;
                float pc1 = r1 * x0 + r4 * x1 + r7 * x2;
                float pc2 = r2 * x0 + r5 * x1 + r8 * x2;
                float w = FOCALC / pc2;               // one div, shared by u,v
                float u = pc0 * w + PXC;
                float v = pc1 * w + PYC;
                float du = u - bl[j];
                float dv = v - bl[NJ + j];
                fs += du * du + dv * dv;
            };
            if (half == 0) {
                #pragma unroll
                for (int j = 0; j < 8; ++j) term(j);
            } else {
                #pragma unroll
                for (int j = 8; j < NJ; ++j) term(j);
            }
            acc += fs / 30.0f;   // half-frame contribution; halves sum to mse
        }
        __syncthreads();   // drains next-tile loads (issued pre-compute) + LDS reuse
        cur ^= 1;
    }

    float bsum = block_reduce_sum(acc);
    if (threadIdx.x == 0) partial[blockIdx.x] = bsum;
}

__global__ __launch_bounds__(THREADS) void finalize_kernel(
        const float* __restrict__ partial,
        const float* __restrict__ pose3d,
        float* __restrict__ out,
        int nPartial) {
    float acc = 0.0f;
    for (int i = threadIdx.x; i < nPartial; i += blockDim.x)
        acc += partial[i];
    acc = block_reduce_sum(acc);
    if (threadIdx.x == 0) {
        const int lb[6][2] = {{0,1},{1,2},{2,3},{8,9},{9,10},{10,11}};
        const int rb[6][2] = {{0,4},{4,5},{5,6},{8,12},{12,13},{13,14}};
        float sym = 0.0f;
        #pragma unroll
        for (int bb = 0; bb < 6; ++bb) {
            float ll = 0.0f, lr = 0.0f;
            #pragma unroll
            for (int k = 0; k < 3; ++k) {
                float dl = pose3d[k * NJ + lb[bb][0]] - pose3d[k * NJ + lb[bb][1]];
                float dr = pose3d[k * NJ + rb[bb][0]] - pose3d[k * NJ + rb[bb][1]];
                ll += dl * dl;
                lr += dr * dr;
            }
            float d = ll - lr;
            sym += d * d;
        }
        sym /= 6.0f;
        out[0] = 1.0f * sym + 1.0f * acc;
    }
}

extern "C" void kernel_launch(void* const* d_in, const int* in_sizes, int n_in,
                              void* d_out, int out_size, void* d_ws, size_t ws_size,
                              hipStream_t stream) {
    const float* pose3d = (const float*)d_in[0];
    const float* bone2d = (const float*)d_in[1];
    const float* R      = (const float*)d_in[2];
    const float* C      = (const float*)d_in[3];
    float* out = (float*)d_out;
    float* partial = (float*)d_ws;

    int N = in_sizes[3] / 3;  // C_drone has N*3 elements

    proj_partial_kernel<<<BLOCKS, THREADS, 0, stream>>>(pose3d, bone2d, R, C, partial, N);
    finalize_kernel<<<1, THREADS, 0, stream>>>(partial, pose3d, out, BLOCKS);
}